// Round 10
// baseline (442.958 us; speedup 1.0000x reference)
//
#include <hip/hip_runtime.h>
#include <math.h>

typedef __attribute__((ext_vector_type(8))) _Float16 half8;
typedef __attribute__((ext_vector_type(4))) _Float16 half4;
typedef __attribute__((ext_vector_type(4))) float f32x4;

#define B_TOT   65536
#define ROWS    32
#define NBLK    (B_TOT / ROWS)      // 2048
#define THREADS 512
#define LOG2PI_F 1.8378770664093453f
#define HALF_N_LOG2PI (0.5f * 64.0f * LOG2PI_F)
#define LOG_1EM8 (-18.420680743952367f)

// ws layout (bytes)
#define WS_W2P  0                    // 2 MB fp16 packed
#define WS_W1P  (2*1024*1024)        // 128 KB fp16 packed
#define WS_PART (WS_W1P + 256*1024)

__device__ __forceinline__ float eluf(float v) {
    return v > 0.0f ? v : expm1f(v);
}

// src fp32 [Kd][1024] -> dst fp16 packed [(Kd/32)][1024 n][32 k]
__global__ __launch_bounds__(256)
void pack_f16(const float* __restrict__ src, _Float16* __restrict__ dst, int Kd)
{
    __shared__ float ts[64][65];
    const int t = threadIdx.x;
    const int k0 = blockIdx.x * 64, n0 = blockIdx.y * 64;
    {
        int r = t >> 2, c4 = t & 3;
        for (int i = 0; i < 4; ++i) {
            int cc = i * 4 + c4;
            float4 v = *(const float4*)&src[(size_t)(k0 + r) * 1024 + n0 + cc * 4];
            ts[r][cc*4+0] = v.x; ts[r][cc*4+1] = v.y;
            ts[r][cc*4+2] = v.z; ts[r][cc*4+3] = v.w;
        }
    }
    __syncthreads();
    {
        int n = t >> 2;
        for (int i = 0; i < 4; ++i) {
            int kk = (i * 4 + (t & 3)) * 4;      // 0..60, 4-aligned
            int k = k0 + kk;
            half4 h;
            h.x = (_Float16)ts[kk+0][n];
            h.y = (_Float16)ts[kk+1][n];
            h.z = (_Float16)ts[kk+2][n];
            h.w = (_Float16)ts[kk+3][n];
            size_t off = (size_t)(k >> 5) * 32768 + (size_t)(n0 + n) * 32 + (k & 31);
            *(half4*)&dst[off] = h;
        }
    }
}

// 512-thread blocks: the only shape observed to get 128 arch VGPRs (round 2).
// 8 waves x 128 cols, acc[2][8]=64 regs; LDS ~70 KB -> 2 blocks/CU.
__global__ __launch_bounds__(THREADS, 2)
void fused_mdn(const float* __restrict__ x, const float* __restrict__ y,
               const _Float16* __restrict__ W1P, const float* __restrict__ b1,
               const _Float16* __restrict__ W2P, const float* __restrict__ b2,
               const float* __restrict__ Wp1, const float* __restrict__ bp1,
               const float* __restrict__ Wp2, const float* __restrict__ bp2,
               float* __restrict__ partials)
{
    __shared__ __align__(16) _Float16 hs[ROWS * 1024];  // 64 KB: h fp16 -> iv fp32 -> xp+tpi fp32
    __shared__ __align__(16) _Float16 xs[ROWS * 64];    // 4 KB: x fp16 swizzled
    __shared__ float lps[256];                          // 1 KB
    __shared__ float vrs[256];                          // 1 KB
    __shared__ float lses[ROWS];                        // 128 B

    const int t   = threadIdx.x;
    const int q   = blockIdx.x;
    const int w   = t >> 6;      // 0..7, wave owns cols [w*128, w*128+128)
    const int l   = t & 63;
    const int g   = l >> 4;
    const int l15 = l & 15;

    // ---------- phase 0: stage x rows (fp16, swizzled) ----------
    {
        const float4* x4 = (const float4*)x;
        int r = t >> 4, c = t & 15;          // 512 = 32 rows x 16
        float4 v = x4[(size_t)(q * ROWS + r) * 16 + c];
        float vv[4] = {v.x, v.y, v.z, v.w};
        #pragma unroll
        for (int i = 0; i < 4; ++i) {
            int col = c * 4 + i;
            xs[r * 64 + (col ^ ((r & 7) << 3))] = (_Float16)vv[i];
        }
    }
    __syncthreads();

    f32x4 acc[2][8];

    // ---------- phase 1: h = elu(x @ W1 + b1), fp16 MFMA ----------
    #pragma unroll
    for (int ct = 0; ct < 8; ++ct) {
        float bv = b1[w * 128 + ct * 16 + l15];
        acc[0][ct] = (f32x4){bv, bv, bv, bv};
        acc[1][ct] = (f32x4){bv, bv, bv, bv};
    }
    #pragma unroll
    for (int k0 = 0; k0 < 64; k0 += 32) {
        half8 aF[2];
        #pragma unroll
        for (int rt = 0; rt < 2; ++rt) {
            int row = rt * 16 + l15;
            aF[rt] = *(const half8*)&xs[row * 64 + ((k0 + 8 * g) ^ ((row & 7) << 3))];
        }
        #pragma unroll
        for (int hf = 0; hf < 2; ++hf) {
            half8 bF[4];
            #pragma unroll
            for (int cc = 0; cc < 4; ++cc) {
                int ct = hf * 4 + cc;
                size_t off = (size_t)(k0 >> 5) * 32768 + (size_t)(w * 128 + ct * 16 + l15) * 32 + 8 * g;
                bF[cc] = *(const half8*)&W1P[off];
            }
            #pragma unroll
            for (int cc = 0; cc < 4; ++cc)
                #pragma unroll
                for (int rt = 0; rt < 2; ++rt)
                    acc[rt][hf * 4 + cc] = __builtin_amdgcn_mfma_f32_16x16x32_f16(aF[rt], bF[cc], acc[rt][hf * 4 + cc], 0, 0, 0);
        }
    }
    // epilogue: ELU -> fp16 -> hs (swizzled)
    #pragma unroll
    for (int rt = 0; rt < 2; ++rt)
        #pragma unroll
        for (int ct = 0; ct < 8; ++ct)
            #pragma unroll
            for (int rg = 0; rg < 4; ++rg) {
                float v = eluf(acc[rt][ct][rg]);
                int row = rt * 16 + 4 * g + rg;
                int col = w * 128 + ct * 16 + l15;
                hs[row * 1024 + (col ^ ((row & 7) << 3))] = (_Float16)v;
            }
    __syncthreads();

    // ---------- phase 2: fhatx = h @ W2 + b2, fp16 MFMA, 2-stage B prefetch ----------
    #pragma unroll
    for (int ct = 0; ct < 8; ++ct) {
        float bv = b2[w * 128 + ct * 16 + l15];
        acc[0][ct] = (f32x4){bv, bv, bv, bv};
        acc[1][ct] = (f32x4){bv, bv, bv, bv};
    }
    int boff[8];
    #pragma unroll
    for (int ct = 0; ct < 8; ++ct)
        boff[ct] = (w * 128 + ct * 16 + l15) * 32 + 8 * g;

    half8 bC[4];
    #pragma unroll
    for (int cc = 0; cc < 4; ++cc) bC[cc] = *(const half8*)&W2P[boff[cc]];

    for (int k0 = 0; k0 < 1024; k0 += 32) {
        const size_t kb = (size_t)(k0 >> 5) * 32768;
        half8 aF[2];
        #pragma unroll
        for (int rt = 0; rt < 2; ++rt) {
            int row = rt * 16 + l15;
            aF[rt] = *(const half8*)&hs[row * 1024 + ((k0 + 8 * g) ^ ((row & 7) << 3))];
        }
        // half 0: compute ct 0..3 with bC, prefetch ct 4..7 of same k-tile
        half8 bN[4];
        #pragma unroll
        for (int cc = 0; cc < 4; ++cc) bN[cc] = *(const half8*)&W2P[kb + boff[4 + cc]];
        #pragma unroll
        for (int cc = 0; cc < 4; ++cc)
            #pragma unroll
            for (int rt = 0; rt < 2; ++rt)
                acc[rt][cc] = __builtin_amdgcn_mfma_f32_16x16x32_f16(aF[rt], bC[cc], acc[rt][cc], 0, 0, 0);
        // half 1: compute ct 4..7 with bN, prefetch next k-tile's ct 0..3
        if (k0 + 32 < 1024) {
            #pragma unroll
            for (int cc = 0; cc < 4; ++cc) bC[cc] = *(const half8*)&W2P[kb + 32768 + boff[cc]];
        }
        #pragma unroll
        for (int cc = 0; cc < 4; ++cc)
            #pragma unroll
            for (int rt = 0; rt < 2; ++rt)
                acc[rt][4 + cc] = __builtin_amdgcn_mfma_f32_16x16x32_f16(aF[rt], bN[cc], acc[rt][4 + cc], 0, 0, 0);
    }
    __syncthreads();   // all hs reads done; hs region becomes iv (fp32)

    // ---------- phase 3: MDN log-prob, in-register ----------
    // wave w<4: mu for mixes {2w, 2w+1}; wave w>=4: var_raw for mixes {2(w-4), 2(w-4)+1}.
    float* iv_lds = (float*)hs;     // [8 mix][32 row][64 n] fp32 = 64 KB

    if (w >= 4) {
        const int jb = 2 * (w & 3);
        float rs[2][2][4];
        #pragma unroll
        for (int rt = 0; rt < 2; ++rt)
            #pragma unroll
            for (int hf = 0; hf < 2; ++hf)
                #pragma unroll
                for (int rg = 0; rg < 4; ++rg) rs[rt][hf][rg] = 0.0f;
        #pragma unroll
        for (int rt = 0; rt < 2; ++rt)
            #pragma unroll
            for (int ct = 0; ct < 8; ++ct)
                #pragma unroll
                for (int rg = 0; rg < 4; ++rg) {
                    float vr = acc[rt][ct][rg];
                    float vre = fmaxf(vr, LOG_1EM8);
                    float iv = (vr >= LOG_1EM8) ? expf(-vr) : 1e8f;
                    rs[rt][ct >> 2][rg] += vre;
                    int j = jb + (ct >> 2);
                    int row = rt * 16 + 4 * g + rg;
                    int nw = ((ct & 3) * 16 + l15) ^ ((g & 1) << 4);
                    iv_lds[(j * 32 + row) * 64 + nw] = iv;
                }
        #pragma unroll
        for (int rt = 0; rt < 2; ++rt)
            #pragma unroll
            for (int hf = 0; hf < 2; ++hf)
                #pragma unroll
                for (int rg = 0; rg < 4; ++rg) {
                    float s = rs[rt][hf][rg];
                    s += __shfl_xor(s, 1); s += __shfl_xor(s, 2);
                    s += __shfl_xor(s, 4); s += __shfl_xor(s, 8);
                    rs[rt][hf][rg] = s;
                }
        if (l15 == 0) {
            #pragma unroll
            for (int rt = 0; rt < 2; ++rt)
                #pragma unroll
                for (int hf = 0; hf < 2; ++hf)
                    #pragma unroll
                    for (int rg = 0; rg < 4; ++rg) {
                        int row = rt * 16 + 4 * g + rg;
                        vrs[row * 8 + jb + hf] = rs[rt][hf][rg];
                    }
        }
    } else {
        const int jb = 2 * w;
        // mu-wave: d = y - mu (overlaps var-waves' exp work)
        #pragma unroll
        for (int rt = 0; rt < 2; ++rt)
            #pragma unroll
            for (int ct = 0; ct < 8; ++ct)
                #pragma unroll
                for (int rg = 0; rg < 4; ++rg) {
                    int j = jb + (ct >> 2);
                    int row = rt * 16 + 4 * g + rg;
                    int bprime = 4 * q + (row >> 3) + j * 8192;
                    float yv = y[(size_t)bprime * 64 + (ct & 3) * 16 + l15];
                    acc[rt][ct][rg] = yv - acc[rt][ct][rg];
                }
    }
    __syncthreads();

    if (w < 4) {
        const int jb = 2 * w;
        float rs[2][2][4];
        #pragma unroll
        for (int rt = 0; rt < 2; ++rt)
            #pragma unroll
            for (int hf = 0; hf < 2; ++hf)
                #pragma unroll
                for (int rg = 0; rg < 4; ++rg) rs[rt][hf][rg] = 0.0f;
        #pragma unroll
        for (int rt = 0; rt < 2; ++rt)
            #pragma unroll
            for (int ct = 0; ct < 8; ++ct)
                #pragma unroll
                for (int rg = 0; rg < 4; ++rg) {
                    int j = jb + (ct >> 2);
                    int row = rt * 16 + 4 * g + rg;
                    int nw = ((ct & 3) * 16 + l15) ^ ((g & 1) << 4);
                    float iv = iv_lds[(j * 32 + row) * 64 + nw];
                    float d = acc[rt][ct][rg];
                    rs[rt][ct >> 2][rg] = fmaf(d * d, iv, rs[rt][ct >> 2][rg]);
                }
        #pragma unroll
        for (int rt = 0; rt < 2; ++rt)
            #pragma unroll
            for (int hf = 0; hf < 2; ++hf)
                #pragma unroll
                for (int rg = 0; rg < 4; ++rg) {
                    float s = rs[rt][hf][rg];
                    s += __shfl_xor(s, 1); s += __shfl_xor(s, 2);
                    s += __shfl_xor(s, 4); s += __shfl_xor(s, 8);
                    rs[rt][hf][rg] = s;
                }
        if (l15 == 0) {
            #pragma unroll
            for (int rt = 0; rt < 2; ++rt)
                #pragma unroll
                for (int hf = 0; hf < 2; ++hf)
                    #pragma unroll
                    for (int rg = 0; rg < 4; ++rg) {
                        int row = rt * 16 + 4 * g + rg;
                        int j = jb + hf;
                        float lp = -0.5f * (rs[rt][hf][rg] + vrs[row * 8 + j]) - HALF_N_LOG2PI;
                        lps[((row >> 3) * 8 + j) * 8 + (row & 7)] = lp;
                    }
        }
    }
    __syncthreads();   // iv fully consumed; hs region free

    // ---------- phase 3.5: stage xp rows into hs[0:8KB] ----------
    float* xp  = (float*)hs;          // [32][64] fp32
    float* tpi = (float*)hs + 2048;   // [32][64] fp32
    {
        const float4* x4 = (const float4*)x;
        int o = t >> 4, c = t & 15;
        int bprime = 4 * q + (o >> 3) + (o & 7) * 8192;
        ((float4*)xp)[o * 16 + c] = x4[(size_t)bprime * 16 + c];
    }
    __syncthreads();

    // ---------- phase 4: pi network for 32 outputs ----------
    {
        int c = l, ob = w;   // rows {ob, ob+8, ob+16, ob+24}
        float a0 = bp1[c], a1 = a0, a2 = a0, a3 = a0;
        for (int n = 0; n < 64; ++n) {
            float wv = Wp1[n * 64 + c];
            a0 += xp[(ob +  0) * 64 + n] * wv;
            a1 += xp[(ob +  8) * 64 + n] * wv;
            a2 += xp[(ob + 16) * 64 + n] * wv;
            a3 += xp[(ob + 24) * 64 + n] * wv;
        }
        tpi[(ob +  0) * 64 + c] = eluf(a0);
        tpi[(ob +  8) * 64 + c] = eluf(a1);
        tpi[(ob + 16) * 64 + c] = eluf(a2);
        tpi[(ob + 24) * 64 + c] = eluf(a3);
    }
    __syncthreads();
    if (t < 256) {
        int o = t >> 3, k = t & 7;
        float a = bp2[k];
        for (int n = 0; n < 64; ++n) a += tpi[o * 64 + n] * Wp2[n * 8 + k];
        float m = a;
        m = fmaxf(m, __shfl_xor(m, 1));
        m = fmaxf(m, __shfl_xor(m, 2));
        m = fmaxf(m, __shfl_xor(m, 4));
        float e = expf(a - m);
        float sden = e;
        sden += __shfl_xor(sden, 1); sden += __shfl_xor(sden, 2); sden += __shfl_xor(sden, 4);
        float logpi = a - m - logf(sden);
        float v = logpi + lps[o * 8 + k];
        float mv = v;
        mv = fmaxf(mv, __shfl_xor(mv, 1));
        mv = fmaxf(mv, __shfl_xor(mv, 2));
        mv = fmaxf(mv, __shfl_xor(mv, 4));
        float ee = expf(v - mv);
        float ss = ee;
        ss += __shfl_xor(ss, 1); ss += __shfl_xor(ss, 2); ss += __shfl_xor(ss, 4);
        if (k == 0) lses[o] = mv + logf(ss);
    }
    __syncthreads();
    if (t == 0) {
        float p = 0.0f;
        #pragma unroll
        for (int o = 0; o < ROWS; ++o) p += lses[o];
        partials[q] = p;
    }
}

__global__ void reduce_partials(const float* __restrict__ partials, float* __restrict__ out)
{
    __shared__ double red[256];
    int t = threadIdx.x;
    double s = 0.0;
    for (int i = t; i < NBLK; i += 256) s += (double)partials[i];
    red[t] = s;
    __syncthreads();
    for (int w = 128; w > 0; w >>= 1) {
        if (t < w) red[t] += red[t + w];
        __syncthreads();
    }
    if (t == 0) out[0] = (float)(-red[0] / (double)B_TOT);
}

extern "C" void kernel_launch(void* const* d_in, const int* in_sizes, int n_in,
                              void* d_out, int out_size, void* d_ws, size_t ws_size,
                              hipStream_t stream)
{
    const float* x   = (const float*)d_in[0];
    const float* y   = (const float*)d_in[1];
    const float* W1  = (const float*)d_in[2];
    const float* b1  = (const float*)d_in[3];
    const float* W2  = (const float*)d_in[4];
    const float* b2  = (const float*)d_in[5];
    const float* Wp1 = (const float*)d_in[6];
    const float* bp1 = (const float*)d_in[7];
    const float* Wp2 = (const float*)d_in[8];
    const float* bp2 = (const float*)d_in[9];

    char* ws = (char*)d_ws;
    _Float16* W2P = (_Float16*)(ws + WS_W2P);
    _Float16* W1P = (_Float16*)(ws + WS_W1P);
    float* partials = (float*)(ws + WS_PART);

    pack_f16<<<dim3(16, 16), 256, 0, stream>>>(W2, W2P, 1024);
    pack_f16<<<dim3(1, 16), 256, 0, stream>>>(W1, W1P, 64);
    fused_mdn<<<NBLK, THREADS, 0, stream>>>(x, y, W1P, b1, W2P, b2,
                                            Wp1, bp1, Wp2, bp2, partials);
    reduce_partials<<<1, 256, 0, stream>>>(partials, (float*)d_out);
}

// Round 11
// 258.108 us; speedup vs baseline: 1.7162x; 1.7162x over previous
//
#include <hip/hip_runtime.h>
#include <math.h>

typedef __attribute__((ext_vector_type(8))) _Float16 half8;
typedef __attribute__((ext_vector_type(4))) _Float16 half4;
typedef __attribute__((ext_vector_type(4))) float f32x4;

#define B_TOT 65536
#define LOG2PI_F 1.8378770664093453f
#define HALF_N_LOG2PI (0.5f * 64.0f * LOG2PI_F)
#define LOG_1EM8 (-18.420680743952367f)

// ws layout (bytes)
#define WS_W2S  0                      // 2 MiB   fp16 packed+swizzled [32kt][1024n][32kk']
#define WS_W1P  (2u*1024*1024)         // 128 KiB fp16 packed [2kt][1024n][32kk] (plain)
#define WS_LPS  (4u*1024*1024)         // 2 MiB   float lps[65536][8]
#define WS_PART (6u*1024*1024)         // 1 KiB   float partials[256]
#define WS_HP   (8u*1024*1024)         // 128 MiB fp16 h packed [32kt][65536row][32kk']

typedef __attribute__((address_space(3))) unsigned int lds_u32;
typedef const __attribute__((address_space(1))) unsigned int glb_u32;

__device__ __forceinline__ void gload16(const void* g, void* l) {
    __builtin_amdgcn_global_load_lds((glb_u32*)g, (lds_u32*)l, 16, 0, 0);
}

__device__ __forceinline__ float eluf(float v) {
    return v > 0.0f ? v : expm1f(v);
}

// ---------------- pack W1: fp32 [64][1024] -> fp16 [kt][n][32kk] plain ----------------
__global__ __launch_bounds__(256)
void pack_w1(const float* __restrict__ src, _Float16* __restrict__ dst)
{
    __shared__ float ts[64][65];
    const int t = threadIdx.x;
    const int n0 = blockIdx.y * 64;
    {
        int r = t >> 2, c4 = t & 3;
        for (int i = 0; i < 4; ++i) {
            int cc = i * 4 + c4;
            float4 v = *(const float4*)&src[(size_t)r * 1024 + n0 + cc * 4];
            ts[r][cc*4+0] = v.x; ts[r][cc*4+1] = v.y;
            ts[r][cc*4+2] = v.z; ts[r][cc*4+3] = v.w;
        }
    }
    __syncthreads();
    {
        int n = t >> 2;
        for (int i = 0; i < 4; ++i) {
            int k = (i * 4 + (t & 3)) * 4;      // 0..60
            half4 h;
            h.x = (_Float16)ts[k+0][n];
            h.y = (_Float16)ts[k+1][n];
            h.z = (_Float16)ts[k+2][n];
            h.w = (_Float16)ts[k+3][n];
            size_t off = (size_t)(k >> 5) * 32768 + (size_t)(n0 + n) * 32 + (k & 31);
            *(half4*)&dst[off] = h;
        }
    }
}

// ---------------- pack W2: fp32 [1024][1024] -> fp16 [kt][n][32] with k-group swizzle ----------------
// element (k, n) stored at [k>>5][n][ ((slot)<<3) | (k&7) ], slot = ((k>>3)&3) ^ ((n>>1)&3)
__global__ __launch_bounds__(256)
void pack_w2s(const float* __restrict__ src, _Float16* __restrict__ dst)
{
    __shared__ float ts[64][65];
    const int t = threadIdx.x;
    const int k0 = blockIdx.x * 64, n0 = blockIdx.y * 64;
    {
        int r = t >> 2, c4 = t & 3;
        for (int i = 0; i < 4; ++i) {
            int cc = i * 4 + c4;
            float4 v = *(const float4*)&src[(size_t)(k0 + r) * 1024 + n0 + cc * 4];
            ts[r][cc*4+0] = v.x; ts[r][cc*4+1] = v.y;
            ts[r][cc*4+2] = v.z; ts[r][cc*4+3] = v.w;
        }
    }
    __syncthreads();
    {
        int n = t >> 2;
        int ng = n0 + n;
        for (int i = 0; i < 4; ++i) {
            int kl = (i * 4 + (t & 3)) * 4;      // local k, 4-aligned
            int k = k0 + kl;
            half4 h;
            h.x = (_Float16)ts[kl+0][n];
            h.y = (_Float16)ts[kl+1][n];
            h.z = (_Float16)ts[kl+2][n];
            h.w = (_Float16)ts[kl+3][n];
            int kk = k & 31;
            int slot = ((kk >> 3) ^ ((ng >> 1) & 3));
            size_t off = (size_t)(k >> 5) * 32768 + (size_t)ng * 32 + (slot << 3) + (kk & 7);
            *(half4*)&dst[off] = h;
        }
    }
}

// ---------------- K1: h = elu(x @ W1 + b1) -> packed fp16 [kt][grow][32kk'] ----------------
__global__ __launch_bounds__(1024)
void k1_h(const float* __restrict__ x, const _Float16* __restrict__ W1P,
          const float* __restrict__ b1, _Float16* __restrict__ hp)
{
    __shared__ __align__(16) _Float16 xs[32 * 64];
    const int t = threadIdx.x, q = blockIdx.x;
    const int w = t >> 6, l = t & 63, g = l >> 4, l15 = l & 15;

    if (t < 512) {
        const float4* x4 = (const float4*)x;
        int r = t >> 4, c = t & 15;
        float4 v = x4[(size_t)(q * 32 + r) * 16 + c];
        float vv[4] = {v.x, v.y, v.z, v.w};
        #pragma unroll
        for (int i = 0; i < 4; ++i) {
            int col = c * 4 + i;
            xs[r * 64 + (col ^ ((r & 7) << 3))] = (_Float16)vv[i];
        }
    }
    __syncthreads();

    f32x4 acc[2][4];
    #pragma unroll
    for (int ct = 0; ct < 4; ++ct) {
        float bv = b1[w * 64 + ct * 16 + l15];
        acc[0][ct] = (f32x4){bv, bv, bv, bv};
        acc[1][ct] = (f32x4){bv, bv, bv, bv};
    }
    #pragma unroll
    for (int k0 = 0; k0 < 64; k0 += 32) {
        half8 bF[4];
        #pragma unroll
        for (int ct = 0; ct < 4; ++ct) {
            size_t off = (size_t)(k0 >> 5) * 32768 + (size_t)(w * 64 + ct * 16 + l15) * 32 + 8 * g;
            bF[ct] = *(const half8*)&W1P[off];
        }
        half8 aF[2];
        #pragma unroll
        for (int rt = 0; rt < 2; ++rt) {
            int row = rt * 16 + l15;
            aF[rt] = *(const half8*)&xs[row * 64 + ((k0 + 8 * g) ^ ((row & 7) << 3))];
        }
        #pragma unroll
        for (int ct = 0; ct < 4; ++ct)
            #pragma unroll
            for (int rt = 0; rt < 2; ++rt)
                acc[rt][ct] = __builtin_amdgcn_mfma_f32_16x16x32_f16(aF[rt], bF[ct], acc[rt][ct], 0, 0, 0);
    }
    // ELU -> packed global h write (swizzled k-groups)
    #pragma unroll
    for (int rt = 0; rt < 2; ++rt)
        #pragma unroll
        for (int ct = 0; ct < 4; ++ct)
            #pragma unroll
            for (int rg = 0; rg < 4; ++rg) {
                float v = eluf(acc[rt][ct][rg]);
                int grow = q * 32 + rt * 16 + 4 * g + rg;
                int col = w * 64 + ct * 16 + l15;
                int kk = col & 31;
                int slot = ((kk >> 3) ^ ((grow >> 1) & 3));
                hp[((size_t)(col >> 5) * 65536 + grow) * 32 + (slot << 3) + (kk & 7)] = (_Float16)v;
            }
}

// ---------------- K2: fhatx = h @ W2 + b2 (tiled, LDS dbuf) + in-register lp epilogue ----------------
// block: 128 rows x [mu 128 cols | var 128 cols] of col-group j -> mixes {2j, 2j+1} complete
__global__ __launch_bounds__(512)
void k2_gemm2(const _Float16* __restrict__ hp, const _Float16* __restrict__ W2S,
              const float* __restrict__ b2, const float* __restrict__ y,
              float* __restrict__ lps)
{
    __shared__ __align__(16) _Float16 Ab[2][4096];   // 2 x 8 KB  [row' 128][32k]
    __shared__ __align__(16) _Float16 Bb[2][8192];   // 2 x 16 KB [n' 256][32k] (mu 0..127, var 128..255)
    __shared__ float lpp[128][2][2];                 // 2 KB [row'][mixloc][half]

    const int t = threadIdx.x;
    const int RT = blockIdx.x;     // 0..511 row tile
    const int j  = blockIdx.y;     // 0..3 col group
    const int w = t >> 6, l = t & 63, g = l >> 4, l15 = l & 15;
    const int wr = w >> 2, wc = w & 3;

    // B LDS row (n') per col-frag
    int bn[4];
    bn[0] = (wc >> 1) * 64 + (wc & 1) * 32 + l15;
    bn[1] = bn[0] + 16;
    bn[2] = bn[0] + 128;
    bn[3] = bn[1] + 128;

    // acc init with bias
    f32x4 acc[4][4];
    #pragma unroll
    for (int fc = 0; fc < 4; ++fc) {
        int colg = (fc < 2) ? (j * 128 + bn[fc]) : (512 + j * 128 + bn[fc] - 128);
        float bv = b2[colg];
        #pragma unroll
        for (int fr = 0; fr < 4; ++fr) acc[fr][fc] = (f32x4){bv, bv, bv, bv};
    }

    const char* hpb  = (const char*)hp;
    const char* w2sb = (const char*)W2S;
    const int lane16 = l * 16;

    // prologue stage kt=0
    {
        size_t ga = ((size_t)0 * 65536 + (size_t)RT * 128) * 64 + w * 1024 + lane16;
        gload16(hpb + ga, (char*)&Ab[0][0] + w * 1024);
        size_t gb0 = ((size_t)0 * 1024 + j * 128) * 64 + w * 1024 + lane16;
        gload16(w2sb + gb0, (char*)&Bb[0][0] + w * 1024);
        size_t gb1 = ((size_t)0 * 1024 + 512 + j * 128) * 64 + w * 1024 + lane16;
        gload16(w2sb + gb1, (char*)&Bb[0][0] + 8192 + w * 1024);
    }
    __syncthreads();

    for (int kt = 0; kt < 32; ++kt) {
        int cur = kt & 1;
        if (kt < 31) {
            int nx = cur ^ 1;
            size_t ga = ((size_t)(kt + 1) * 65536 + (size_t)RT * 128) * 64 + w * 1024 + lane16;
            gload16(hpb + ga, (char*)&Ab[nx][0] + w * 1024);
            size_t gb0 = ((size_t)(kt + 1) * 1024 + j * 128) * 64 + w * 1024 + lane16;
            gload16(w2sb + gb0, (char*)&Bb[nx][0] + w * 1024);
            size_t gb1 = ((size_t)(kt + 1) * 1024 + 512 + j * 128) * 64 + w * 1024 + lane16;
            gload16(w2sb + gb1, (char*)&Bb[nx][0] + 8192 + w * 1024);
        }
        half8 aF[4], bF[4];
        #pragma unroll
        for (int fr = 0; fr < 4; ++fr) {
            int r = wr * 64 + fr * 16 + l15;
            aF[fr] = *(const half8*)((const char*)&Ab[cur][0] + r * 64 + ((g ^ ((r >> 1) & 3)) << 4));
        }
        #pragma unroll
        for (int fc = 0; fc < 4; ++fc) {
            int n = bn[fc];
            bF[fc] = *(const half8*)((const char*)&Bb[cur][0] + n * 64 + ((g ^ ((n >> 1) & 3)) << 4));
        }
        #pragma unroll
        for (int fc = 0; fc < 4; ++fc)
            #pragma unroll
            for (int fr = 0; fr < 4; ++fr)
                acc[fr][fc] = __builtin_amdgcn_mfma_f32_16x16x32_f16(aF[fr], bF[fc], acc[fr][fc], 0, 0, 0);
        __syncthreads();
    }

    // ---- epilogue: lp partials fully in-register (mu fc pairs var fc+2 in SAME lane) ----
    const int jj = j * 2 + (wc >> 1);
    float s[4][4];
    #pragma unroll
    for (int fr = 0; fr < 4; ++fr)
        #pragma unroll
        for (int rg = 0; rg < 4; ++rg) s[fr][rg] = 0.0f;

    #pragma unroll
    for (int fc = 0; fc < 2; ++fc) {
        int n = (wc & 1) * 32 + fc * 16 + l15;
        #pragma unroll
        for (int fr = 0; fr < 4; ++fr)
            #pragma unroll
            for (int rg = 0; rg < 4; ++rg) {
                int grow = RT * 128 + wr * 64 + fr * 16 + 4 * g + rg;
                int bp = (grow >> 3) + jj * 8192;
                float yv = y[(size_t)bp * 64 + n];
                float mu = acc[fr][fc][rg];
                float vr = acc[fr][fc + 2][rg];
                float vre = fmaxf(vr, LOG_1EM8);
                float iv = (vr >= LOG_1EM8) ? expf(-vr) : 1e8f;
                float d = yv - mu;
                s[fr][rg] += fmaf(d * d, iv, vre);
            }
    }
    #pragma unroll
    for (int fr = 0; fr < 4; ++fr)
        #pragma unroll
        for (int rg = 0; rg < 4; ++rg) {
            float v = s[fr][rg];
            v += __shfl_xor(v, 1); v += __shfl_xor(v, 2);
            v += __shfl_xor(v, 4); v += __shfl_xor(v, 8);
            s[fr][rg] = v;
        }
    if (l15 == 0) {
        #pragma unroll
        for (int fr = 0; fr < 4; ++fr)
            #pragma unroll
            for (int rg = 0; rg < 4; ++rg)
                lpp[wr * 64 + fr * 16 + 4 * g + rg][wc >> 1][wc & 1] = s[fr][rg];
    }
    __syncthreads();
    if (t < 256) {
        int row_l = t >> 1, m = t & 1;
        float lp = -0.5f * (lpp[row_l][m][0] + lpp[row_l][m][1]) - HALF_N_LOG2PI;
        int grow = RT * 128 + row_l;
        int bp = (grow >> 3) + (j * 2 + m) * 8192;
        lps[(size_t)bp * 8 + (grow & 7)] = lp;
    }
}

// ---------------- K3: pi network + log-softmax + logsumexp + block partial ----------------
__global__ __launch_bounds__(256)
void k3_pi(const float* __restrict__ x, const float* __restrict__ Wp1,
           const float* __restrict__ bp1, const float* __restrict__ Wp2,
           const float* __restrict__ bp2, const float* __restrict__ lps,
           float* __restrict__ partials)
{
    __shared__ float xsl[256][65];
    __shared__ float w1s[64][65];
    __shared__ float w2s[64][8];
    __shared__ float wsum[4];
    const int t = threadIdx.x;
    const int b0 = blockIdx.x * 256;

    {
        const float4* x4 = (const float4*)x;
        for (int i = 0; i < 16; ++i) {
            int idx = t + i * 256;
            int r = idx >> 4, c = idx & 15;
            float4 v = x4[(size_t)(b0 + r) * 16 + c];
            xsl[r][c*4+0] = v.x; xsl[r][c*4+1] = v.y;
            xsl[r][c*4+2] = v.z; xsl[r][c*4+3] = v.w;
        }
        for (int i = 0; i < 16; ++i) {
            int idx = t + i * 256;
            int r = idx >> 6, c = idx & 63;
            w1s[r][c] = Wp1[r * 64 + c];
        }
        ((float*)w2s)[t] = Wp2[t];
        ((float*)w2s)[t + 256] = Wp2[t + 256];
    }
    __syncthreads();

    float hid[64];
    #pragma unroll
    for (int c = 0; c < 64; ++c) hid[c] = bp1[c];
    for (int n = 0; n < 64; ++n) {
        float xv = xsl[t][n];
        #pragma unroll
        for (int c = 0; c < 64; ++c) hid[c] = fmaf(xv, w1s[n][c], hid[c]);
    }
    float lg[8];
    #pragma unroll
    for (int k = 0; k < 8; ++k) lg[k] = bp2[k];
    #pragma unroll
    for (int c = 0; c < 64; ++c) {
        float e = eluf(hid[c]);
        #pragma unroll
        for (int k = 0; k < 8; ++k) lg[k] = fmaf(e, w2s[c][k], lg[k]);
    }
    float4 lpa = *(const float4*)&lps[(size_t)(b0 + t) * 8];
    float4 lpb = *(const float4*)&lps[(size_t)(b0 + t) * 8 + 4];
    float lp[8] = {lpa.x, lpa.y, lpa.z, lpa.w, lpb.x, lpb.y, lpb.z, lpb.w};

    float m1 = lg[0];
    #pragma unroll
    for (int k = 1; k < 8; ++k) m1 = fmaxf(m1, lg[k]);
    float den = 0.0f;
    #pragma unroll
    for (int k = 0; k < 8; ++k) den += expf(lg[k] - m1);
    float lden = logf(den);

    float v0 = lg[0] - m1 - lden + lp[0];
    float m2 = v0;
    float vv[8]; vv[0] = v0;
    #pragma unroll
    for (int k = 1; k < 8; ++k) {
        vv[k] = lg[k] - m1 - lden + lp[k];
        m2 = fmaxf(m2, vv[k]);
    }
    float s2 = 0.0f;
    #pragma unroll
    for (int k = 0; k < 8; ++k) s2 += expf(vv[k] - m2);
    float loss = m2 + logf(s2);

    // deterministic block reduce
    float ssum = loss;
    ssum += __shfl_xor(ssum, 1);  ssum += __shfl_xor(ssum, 2);
    ssum += __shfl_xor(ssum, 4);  ssum += __shfl_xor(ssum, 8);
    ssum += __shfl_xor(ssum, 16); ssum += __shfl_xor(ssum, 32);
    if ((t & 63) == 0) wsum[t >> 6] = ssum;
    __syncthreads();
    if (t == 0) partials[blockIdx.x] = wsum[0] + wsum[1] + wsum[2] + wsum[3];
}

// ---------------- K4: final reduce ----------------
__global__ void k4_reduce(const float* __restrict__ partials, float* __restrict__ out)
{
    __shared__ double red[256];
    int t = threadIdx.x;
    red[t] = (double)partials[t];
    __syncthreads();
    for (int s = 128; s > 0; s >>= 1) {
        if (t < s) red[t] += red[t + s];
        __syncthreads();
    }
    if (t == 0) out[0] = (float)(-red[0] / (double)B_TOT);
}

extern "C" void kernel_launch(void* const* d_in, const int* in_sizes, int n_in,
                              void* d_out, int out_size, void* d_ws, size_t ws_size,
                              hipStream_t stream)
{
    const float* x   = (const float*)d_in[0];
    const float* y   = (const float*)d_in[1];
    const float* W1  = (const float*)d_in[2];
    const float* b1  = (const float*)d_in[3];
    const float* W2  = (const float*)d_in[4];
    const float* b2  = (const float*)d_in[5];
    const float* Wp1 = (const float*)d_in[6];
    const float* bp1 = (const float*)d_in[7];
    const float* Wp2 = (const float*)d_in[8];
    const float* bp2 = (const float*)d_in[9];

    char* ws = (char*)d_ws;
    _Float16* W2S = (_Float16*)(ws + WS_W2S);
    _Float16* W1P = (_Float16*)(ws + WS_W1P);
    float* lps      = (float*)(ws + WS_LPS);
    float* partials = (float*)(ws + WS_PART);
    _Float16* hp    = (_Float16*)(ws + WS_HP);

    pack_w2s<<<dim3(16, 16), 256, 0, stream>>>(W2, W2S);
    pack_w1<<<dim3(1, 16), 256, 0, stream>>>(W1, W1P);
    k1_h<<<2048, 1024, 0, stream>>>(x, W1P, b1, hp);
    k2_gemm2<<<dim3(512, 4), 512, 0, stream>>>(hp, W2S, b2, y, lps);
    k3_pi<<<256, 256, 0, stream>>>(x, Wp1, bp1, Wp2, bp2, lps, partials);
    k4_reduce<<<1, 256, 0, stream>>>(partials, (float*)d_out);
}